// Round 5
// baseline (363.100 us; speedup 1.0000x reference)
//
#include <hip/hip_runtime.h>
#include <stdint.h>

#define S 64
#define NSQ 32
#define Lc 2048
#define Cc 512
#define Ec 128
#define OUT_H (S*NSQ*Lc)   /* 4194304 */

typedef __bf16 bf16x8 __attribute__((ext_vector_type(8)));
typedef float floatx4 __attribute__((ext_vector_type(4)));

__device__ __forceinline__ unsigned short f2bf(float f){
  union { float f; uint32_t u; } v; v.f = f;
  uint32_t r = v.u + 0x7fffu + ((v.u >> 16) & 1u);
  return (unsigned short)(r >> 16);
}

// ---------------------------------------------------------------------------
// k_prep: dynamic weights w[s][c][k], b[s][c]; W1->bf16; W2 rearrange->bf16;
// zero logdet.   grid 512 x 256
// ---------------------------------------------------------------------------
__global__ void k_prep(const float* __restrict__ emb,
                       const float* __restrict__ Wa, const float* __restrict__ ba,
                       const float* __restrict__ Wb, const float* __restrict__ bb,
                       const float* __restrict__ W1, const float* __restrict__ W2,
                       float* __restrict__ dynW, float* __restrict__ dynB,
                       unsigned short* __restrict__ W1bf, unsigned short* __restrict__ W2bf,
                       float* __restrict__ out)
{
  __shared__ float embl[Ec];
  int tid = threadIdx.x;
  int b = blockIdx.x;          // 512 blocks, 8 per sample
  int s = b >> 3;
  int o = ((b & 7) << 8) | tid;   // 0..2047 (1536 dynW dots + 512 dynB dots)
  if (tid < Ec) embl[tid] = emb[s*Ec + tid];
  __syncthreads();
  const float* row; float bias; float* dst;
  if (o < 1536) { row = Wa + o*Ec; bias = ba[o]; dst = dynW + s*1536 + o; }
  else { int c = o - 1536; row = Wb + c*Ec; bias = bb[c]; dst = dynB + s*Cc + c; }
  float acc = bias;
  const float4* r4 = (const float4*)row;
  #pragma unroll 8
  for (int e = 0; e < Ec/4; e++) {
    float4 rv = r4[e];
    acc += embl[4*e]*rv.x + embl[4*e+1]*rv.y + embl[4*e+2]*rv.z + embl[4*e+3]*rv.w;
  }
  *dst = acc;

  int gtid = b*256 + tid;      // 0..131071
  // W1 convert: 262144 elems, 2/thread. W1 is [o][c][1] row-major == [o][c].
  {
    float2 wv = ((const float2*)W1)[gtid];
    W1bf[2*gtid]   = f2bf(wv.x);
    W1bf[2*gtid+1] = f2bf(wv.y);
  }
  // W2 rearrange: dst [k][j][c] <- src [j][c][k]  (49152 elems)
  if (gtid < 3*32*Cc) {
    int k = gtid >> 14;
    int rem = gtid & 16383;
    int j = rem >> 9, c = rem & 511;
    W2bf[gtid] = f2bf(W2[j*1536 + c*3 + k]);
  }
  if (gtid < S) out[OUT_H + gtid] = 0.f;   // logdet accumulators
}

// ---------------------------------------------------------------------------
// k_fused2: 8-wave block per (l-tile, sample); 2 blocks/CU (LDS 77.9 KB).
//   phase A: acc[512 o][64 ll] = W1 @ x, x computed on the fly (BK=32,
//            one h-row per chunk). A-frags (W1) loaded DIRECTLY from L2;
//            only x staged in LDS (Bs [64][40]).
//   x2t:     [66][520] bf16 = relu(acc+b1), cols lb+ll, rows 64/65 zero.
//   phase B: conv KW=3 via MFMA; W2-frags direct from L2; x2 from LDS.
//   phase C: h1 copy + sigmoid/affine/out + logdet reduce.
// lb = t*62 - 1; valid outputs lo in [0,62).
// ---------------------------------------------------------------------------
__global__ void __launch_bounds__(512, 4) k_fused2(
    const float* __restrict__ h,
    const unsigned short* __restrict__ W1bf, const float* __restrict__ b1,
    const unsigned short* __restrict__ W2bf, const float* __restrict__ b2,
    const float* __restrict__ dynW, const float* __restrict__ dynB,
    float* __restrict__ out)
{
  extern __shared__ char smem[];
  unsigned short* Bs  = (unsigned short*)smem;            // [64][40] (phase A)
  unsigned short* x2t = (unsigned short*)smem;            // [66][520] (aliases Bs)
  float* x3b = (float*)(smem + 68640);                    // [64][36]
  float* red = (float*)(smem + 77856);                    // [8]

  int tid = threadIdx.x;
  int t = blockIdx.x, s = blockIdx.y;
  int lb = t*62 - 1;
  int w = tid >> 6, ln16 = tid & 15, quad = (tid & 63) >> 4;
  int cl = tid & 31, lg = tid >> 5;    // x staging: channel lane, l-group
  int ll0 = lg*4;

  const float* hbase = h + s*(NSQ*Lc);
  const float* dwp = dynW + s*1536;
  const float* dbp = dynB + s*Cc;

  floatx4 acc[4][4];
  #pragma unroll
  for (int mi = 0; mi < 4; mi++)
    #pragma unroll
    for (int ni = 0; ni < 4; ni++)
      acc[mi][ni] = (floatx4){0.f,0.f,0.f,0.f};

  // -------- phase A: 16 K-chunks of 32 channels (one h-row each) --------
  for (int ch = 0; ch < 16; ch++) {
    int c0 = ch*32;
    // A-frags direct from L2 (issued early; barrier drain absorbs latency)
    bf16x8 af[4];
    #pragma unroll
    for (int mi = 0; mi < 4; mi++) {
      int o = w*64 + mi*16 + ln16;
      af[mi] = *(const bf16x8*)&W1bf[o*512 + c0 + quad*8];
    }
    __syncthreads();   // previous chunk's bf reads done; Bs reusable
    // stage Bs: x(c0+cl, ll0..ll0+3), 4 l per thread
    {
      int c = c0 + cl;
      const float* hr = hbase + ch*Lc;       // q = c>>5 = ch
      float w0c = dwp[c*3], w1c = dwp[c*3+1], w2c = dwp[c*3+2];
      float bxc = dbp[c];
      float ph[6];
      int base = lb + ll0 - 1;
      #pragma unroll
      for (int m = 0; m < 6; m++) {
        int hi = base + m;
        ph[m] = ((unsigned)hi < 2048u) ? hr[hi] : 0.f;
      }
      #pragma unroll
      for (int i = 0; i < 4; i++) {
        float v = fmaxf(w0c*ph[i] + w1c*ph[i+1] + w2c*ph[i+2] + bxc, 0.f);
        Bs[(ll0 + i)*40 + cl] = f2bf(v);
      }
    }
    __syncthreads();
    #pragma unroll
    for (int ni = 0; ni < 4; ni++) {
      bf16x8 bf = *(const bf16x8*)&Bs[(ni*16 + ln16)*40 + quad*8];
      #pragma unroll
      for (int mi = 0; mi < 4; mi++)
        acc[mi][ni] = __builtin_amdgcn_mfma_f32_16x16x32_bf16(af[mi], bf, acc[mi][ni], 0, 0, 0);
    }
  }
  __syncthreads();   // all Bs reads done before x2t overwrites the region

  // -------- epilogue A: relu+b1 -> x2t (bf16), zero-pad invalid l --------
  #pragma unroll
  for (int mi = 0; mi < 4; mi++) {
    int o = w*64 + mi*16 + quad*4;
    float4 b1v = *(const float4*)(b1 + o);
    #pragma unroll
    for (int ni = 0; ni < 4; ni++) {
      int ll = ni*16 + ln16;
      int gl = lb + ll;
      ushort4 st;
      if ((unsigned)gl < 2048u) {
        st.x = f2bf(fmaxf(acc[mi][ni][0] + b1v.x, 0.f));
        st.y = f2bf(fmaxf(acc[mi][ni][1] + b1v.y, 0.f));
        st.z = f2bf(fmaxf(acc[mi][ni][2] + b1v.z, 0.f));
        st.w = f2bf(fmaxf(acc[mi][ni][3] + b1v.w, 0.f));
      } else {
        st.x = 0; st.y = 0; st.z = 0; st.w = 0;   // conv2 zero-pad columns
      }
      *(ushort4*)&x2t[ll*520 + o] = st;
    }
  }
  for (int i = tid; i < 520; i += 512)
    ((uint32_t*)&x2t[64*520])[i] = 0u;             // rows 64,65 = 0
  __syncthreads();

  // -------- phase B: KW=3 conv via MFMA; wave = (jh, nh 0..3) --------
  {
    int jh = w & 1, nh = w >> 1;
    floatx4 ca = (floatx4){0.f,0.f,0.f,0.f};
    #pragma unroll
    for (int k = 0; k < 3; k++) {
      const unsigned short* Wk = W2bf + k*16384 + (jh*16 + ln16)*512;
      const unsigned short* xr = x2t + (nh*16 + ln16 + k)*520;
      #pragma unroll
      for (int c0 = 0; c0 < 512; c0 += 32) {
        bf16x8 a0 = *(const bf16x8*)&Wk[c0 + quad*8];
        bf16x8 v0 = *(const bf16x8*)&xr[c0 + quad*8];
        ca = __builtin_amdgcn_mfma_f32_16x16x32_bf16(a0, v0, ca, 0, 0, 0);
      }
    }
    float4 b2v = *(const float4*)(b2 + jh*16 + quad*4);
    int lo = nh*16 + ln16;
    float4 st;
    st.x = ca[0] + b2v.x;
    st.y = ca[1] + b2v.y;
    st.z = ca[2] + b2v.z;
    st.w = ca[3] + b2v.w;
    *(float4*)&x3b[lo*36 + jh*16 + quad*4] = st;
  }
  __syncthreads();

  // -------- phase C: h1 copy + sigmoid/affine/out + logdet --------
  float ld = 0.f;
  #pragma unroll
  for (int i = 0; i < 4; i++) {
    int idx = tid + i*512;           // 0..2047 = (q 0..31) x (lo 0..63)
    int lo = idx & 63, q = idx >> 6;
    int l = t*62 + lo;
    if (lo < 62 && l < 2048) {
      int gi = s*(NSQ*Lc) + q*Lc + l;
      if (q < 16) {
        out[gi] = h[gi];             // h1 passthrough
      } else {
        float sv = 1.f / (1.f + __expf(-(x3b[lo*36 + (q-16)] + 2.f))) + 1e-7f;
        float mv = x3b[lo*36 + (q-16) + 16];
        out[gi] = sv * (h[gi] + mv);
        ld += __logf(sv);
      }
    }
  }
  #pragma unroll
  for (int off = 32; off > 0; off >>= 1) ld += __shfl_down(ld, off);
  if ((tid & 63) == 0) red[w] = ld;
  __syncthreads();
  if (tid == 0) {
    float tot = 0.f;
    #pragma unroll
    for (int i = 0; i < 8; i++) tot += red[i];
    atomicAdd(&out[OUT_H + s], tot);
  }
}

// ---------------------------------------------------------------------------
extern "C" void kernel_launch(void* const* d_in, const int* in_sizes, int n_in,
                              void* d_out, int out_size, void* d_ws, size_t ws_size,
                              hipStream_t stream) {
  const float* h   = (const float*)d_in[0];
  const float* emb = (const float*)d_in[1];
  const float* Wa  = (const float*)d_in[2];
  const float* ba  = (const float*)d_in[3];
  const float* Wb  = (const float*)d_in[4];
  const float* bb  = (const float*)d_in[5];
  const float* W1  = (const float*)d_in[6];
  const float* b1  = (const float*)d_in[7];
  const float* W2  = (const float*)d_in[8];
  const float* b2  = (const float*)d_in[9];
  float* out = (float*)d_out;
  char* ws = (char*)d_ws;

  float* dynW = (float*)(ws + 0);                          // 384 KiB
  float* dynB = (float*)(ws + 393216);                     // 128 KiB
  unsigned short* W1bf = (unsigned short*)(ws + 524288);   // 512 KiB
  unsigned short* W2bf = (unsigned short*)(ws + 1048576);  // 96 KiB
  if (ws_size < 1179648ull) return;                        // ~1.2 MB needed

  const int smem_bytes = 77888;  // x2t 68640 + x3b 9216 + red 32
  (void)hipFuncSetAttribute((const void*)k_fused2,
                            hipFuncAttributeMaxDynamicSharedMemorySize,
                            smem_bytes);

  k_prep<<<512, 256, 0, stream>>>(emb, Wa, ba, Wb, bb, W1, W2,
                                  dynW, dynB, W1bf, W2bf, out);
  k_fused2<<<dim3(34, 64), 512, smem_bytes, stream>>>(h, W1bf, b1, W2bf, b2,
                                                      dynW, dynB, out);
}